// Round 8
// baseline (243.510 us; speedup 1.0000x reference)
//
#include <hip/hip_runtime.h>

typedef __bf16 bf16x8 __attribute__((ext_vector_type(8)));
typedef float f32x4 __attribute__((ext_vector_type(4)));
typedef unsigned short u16x8 __attribute__((ext_vector_type(8)));
typedef unsigned short u16x4 __attribute__((ext_vector_type(4)));
typedef unsigned short u16;
typedef unsigned int u32;

// S=2048, B=2, H=1024, NH=16, HD=64, SCALE=32 (exact)
// Inputs fp32, output fp32. Internal: bf16 MFMA, fp32 accum.
// Max-free softmax (scores tightly bounded); log2(e) folded into q gate -> exp2 direct.

#define LOG2E 1.4426950408889634f

__device__ __forceinline__ float b2f(u16 u) {
  union { unsigned int i; float f; } x; x.i = ((unsigned int)u) << 16; return x.f;
}
__device__ __forceinline__ u16 f2b(float f) {
  union { float f; unsigned int i; } x; x.f = f;
  unsigned int r = (x.i + 0x7fffu + ((x.i >> 16) & 1u)) >> 16;
  return (u16)r;
}
__device__ __forceinline__ float sigm(float x) { return 1.0f / (1.0f + __expf(-x)); }

__device__ __forceinline__ void async16(u16* lds, const u16* g) {
  __builtin_amdgcn_global_load_lds((const __attribute__((address_space(1))) void*)g,
                                   (__attribute__((address_space(3))) void*)lds, 16, 0, 0);
}
__device__ __forceinline__ u16x8 cvt8(f32x4 a, f32x4 b) {
  u16x8 o;
  o[0] = f2b(a[0]); o[1] = f2b(a[1]); o[2] = f2b(a[2]); o[3] = f2b(a[3]);
  o[4] = f2b(b[0]); o[5] = f2b(b[1]); o[6] = f2b(b[2]); o[7] = f2b(b[3]);
  return o;
}

// ---- kernel 0: fp32->bf16 for query + ql_w only (grid 10240)
__global__ __launch_bounds__(256) void k_cvt2(const float4* __restrict__ q, u16x4* __restrict__ qd,
                                              const float4* __restrict__ w, u16x4* __restrict__ wd) {
  int b = blockIdx.x;
  const float4* s; u16x4* d; int i;
  if (b < 8192) { s = q; d = qd; i = b * 256 + threadIdx.x; }
  else          { s = w; d = wd; i = (b - 8192) * 256 + threadIdx.x; }
  float4 x = s[i];
  u16x4 o; o[0] = f2b(x.x); o[1] = f2b(x.y); o[2] = f2b(x.z); o[3] = f2b(x.w);
  d[i] = o;
}

// ---- kernel 1: h = sigmoid(vs) @ vq_w.T + vq_b   (wave per row, 512 blocks)
__global__ __launch_bounds__(256) void k_h(const float* __restrict__ vs,
                                           const float* __restrict__ vq_w,
                                           const float* __restrict__ vq_b,
                                           float* __restrict__ h) {
  __shared__ float svs[1024];
  int t = threadIdx.x;
  for (int i = t; i < 1024; i += 256) svs[i] = sigm(vs[i]);
  __syncthreads();
  int wave = t >> 6, lane = t & 63;
  int row = blockIdx.x * 4 + wave;
  const float4* w4 = (const float4*)(vq_w + (size_t)row * 1024);
  const float4* s4 = (const float4*)svs;
  float acc = 0.f;
#pragma unroll
  for (int k = 0; k < 4; ++k) {
    float4 w = w4[k * 64 + lane];
    float4 s = s4[k * 64 + lane];
    acc += w.x * s.x + w.y * s.y + w.z * s.z + w.w * s.w;
  }
#pragma unroll
  for (int off = 1; off < 64; off <<= 1) acc += __shfl_xor(acc, off);
  if (lane == 0) h[row] = acc + vq_b[row];
}

// ---- kernel 3: qpre = query @ ql_w^T, split-K=4 (grid 1024: kh = bx>>8, K=512 each)
__global__ __launch_bounds__(256) void k_gemm(const u16* __restrict__ A,    // 4096 x 2048 bf16
                                              const u16* __restrict__ Bt,   // 1024 x 2048 bf16
                                              u16* __restrict__ C) {        // 4 x (4096 x 1024)
  __shared__ __align__(16) u16 As[128 * 32];
  __shared__ __align__(16) u16 Bs[128 * 32];
  int tid = threadIdx.x;
  int wave = tid >> 6, lane = tid & 63;
  int l15 = lane & 15, quad = lane >> 4;
  int bx = blockIdx.x & 255;
  int kh = blockIdx.x >> 8;
  int kofs = kh << 9;            // kh * 512
  int m0 = (bx >> 3) * 128;
  int n0 = (bx & 7) * 128;
  int wm = (wave >> 1) * 64, wn = (wave & 1) * 64;
  f32x4 acc[4][4] = {};
  int c1 = tid, c2 = tid + 256;
  const u16* ga1 = A + (size_t)(m0 + (c1 >> 2)) * 2048 + kofs + (c1 & 3) * 8;
  const u16* ga2 = A + (size_t)(m0 + (c2 >> 2)) * 2048 + kofs + (c2 & 3) * 8;
  const u16* gb1 = Bt + (size_t)(n0 + (c1 >> 2)) * 2048 + kofs + (c1 & 3) * 8;
  const u16* gb2 = Bt + (size_t)(n0 + (c2 >> 2)) * 2048 + kofs + (c2 & 3) * 8;
  u16* lA1 = As + wave * 512;
  u16* lA2 = As + 2048 + wave * 512;
  u16* lB1 = Bs + wave * 512;
  u16* lB2 = Bs + 2048 + wave * 512;
  for (int kt = 0; kt < 16; ++kt) {
    async16(lA1, ga1); async16(lA2, ga2);
    async16(lB1, gb1); async16(lB2, gb2);
    ga1 += 32; ga2 += 32; gb1 += 32; gb2 += 32;
    __syncthreads();
    bf16x8 af[4], bfr[4];
#pragma unroll
    for (int mt = 0; mt < 4; ++mt)
      af[mt] = *(const bf16x8*)(As + (wm + mt * 16 + l15) * 32 + quad * 8);
#pragma unroll
    for (int nt = 0; nt < 4; ++nt)
      bfr[nt] = *(const bf16x8*)(Bs + (wn + nt * 16 + l15) * 32 + quad * 8);
#pragma unroll
    for (int mt = 0; mt < 4; ++mt)
#pragma unroll
      for (int nt = 0; nt < 4; ++nt)
        acc[mt][nt] = __builtin_amdgcn_mfma_f32_16x16x32_bf16(af[mt], bfr[nt], acc[mt][nt], 0, 0, 0);
    __syncthreads();
  }
  u16* Cp = C + (size_t)kh * 4096 * 1024;
#pragma unroll
  for (int mt = 0; mt < 4; ++mt) {
#pragma unroll
    for (int r = 0; r < 4; ++r) {
      int m = m0 + wm + mt * 16 + quad * 4 + r;
      u16* crow = Cp + (size_t)m * 1024 + n0 + wn + l15;
#pragma unroll
      for (int nt = 0; nt < 4; ++nt) crow[nt * 16] = f2b(acc[mt][nt][r]);
    }
  }
}

// ---- kernel 4: LN(sum of 4 partials + ql_b)*ln_g+ln_b, * sigm(qs)*sigm(ks)*log2e/32 -> qatt
__global__ __launch_bounds__(256) void k_ln(const u16* __restrict__ qpre,   // 4 x (4096x1024)
                                            const float* __restrict__ ql_b,
                                            const float* __restrict__ ln_g,
                                            const float* __restrict__ ln_b,
                                            const float* __restrict__ qs,
                                            const float* __restrict__ ks,
                                            u16* __restrict__ qatt) {
  int row = blockIdx.x;   // row = s*2 + b
  int t = threadIdx.x;
  const u16* base = qpre + (size_t)row * 1024 + t * 4;
  u16x4 p0 = *(const u16x4*)(base);
  u16x4 p1 = *(const u16x4*)(base + (size_t)4096 * 1024);
  u16x4 p2 = *(const u16x4*)(base + (size_t)2 * 4096 * 1024);
  u16x4 p3 = *(const u16x4*)(base + (size_t)3 * 4096 * 1024);
  float v[4];
  float s = 0.f, ss = 0.f;
#pragma unroll
  for (int j = 0; j < 4; ++j) {
    v[j] = ((b2f(p0[j]) + b2f(p1[j])) + (b2f(p2[j]) + b2f(p3[j]))) + ql_b[t * 4 + j];
    s += v[j]; ss += v[j] * v[j];
  }
#pragma unroll
  for (int off = 1; off < 64; off <<= 1) { s += __shfl_xor(s, off); ss += __shfl_xor(ss, off); }
  __shared__ float red[8];
  int wv = t >> 6, ln = t & 63;
  if (ln == 0) { red[wv] = s; red[4 + wv] = ss; }
  __syncthreads();
  s = red[0] + red[1] + red[2] + red[3];
  ss = red[4] + red[5] + red[6] + red[7];
  float mu = s * (1.f / 1024.f);
  float rstd = rsqrtf(ss * (1.f / 1024.f) - mu * mu + 1e-12f);
  int sidx = row >> 1, b = row & 1;
  int ch0 = t * 4;
  int hh = ch0 >> 6, hd0 = ch0 & 63;
  u16* dst = qatt + ((size_t)(b * 16 + hh) * 2048 + sidx) * 64 + hd0;
#pragma unroll
  for (int j = 0; j < 4; ++j) {
    int ch = ch0 + j;
    float gate = sigm(qs[ch]) * sigm(ks[ch]) * (LOG2E / 32.0f);
    float y = (v[j] - mu) * rstd * ln_g[ch] + ln_b[ch];
    dst[j] = f2b(y * gate);
  }
}

// ---- kernel 5: flash attention, 128q tiles, K+V double-buffered LDS, ONE barrier/iter.
// K/V read DIRECTLY from fp32 globals; bf16 conversion (RNE f2b, bit-identical to cvt kernel)
// happens in the register staging path. grid 512: bh = bx & 31 (XCD locality), qt = bx>>5.
__global__ __launch_bounds__(256, 2) void k_attn(const u16* __restrict__ qatt,
                                                 const float* __restrict__ key,
                                                 const float* __restrict__ value,
                                                 const float* __restrict__ hbuf,
                                                 float* __restrict__ out) {
  int bh = blockIdx.x & 31;
  int qt = blockIdx.x >> 5;
  int b = bh >> 4, h = bh & 15;
  int tid = threadIdx.x, wave = tid >> 6, lane = tid & 63;
  int l15 = lane & 15, quad = lane >> 4;
  int q0 = qt * 128;

  __shared__ __align__(16) u16 Kt[2][64 * 72];   // [buf][key][ch]
  __shared__ __align__(16) u16 Vt[2][64 * 72];   // [buf][ch][key]
  __shared__ __align__(16) u16 Pb[4][32 * 72];   // per-wave P, [qrow 0..31][key]

  // Q frags: frag f covers queries q0 + f*64 + wave*16 + [0,16)
  bf16x8 qf[2][2];
#pragma unroll
  for (int f = 0; f < 2; ++f) {
    const u16* qrow = qatt + ((size_t)bh * 2048 + q0 + f * 64 + wave * 16 + l15) * 64 + quad * 8;
    qf[f][0] = *(const bf16x8*)qrow;
    qf[f][1] = *(const bf16x8*)(qrow + 32);
  }

  const float* kb = key + (size_t)b * 1024 + (size_t)h * 64;
  const float* vb = value + (size_t)b * 1024 + (size_t)h * 64;
  u16* Pw = Pb[wave];

  // V staging: lane covers keys 2p,2p+1 (p=lane&31), 8 ch at chbase (fp32 source)
  int p = lane & 31;
  int chbase = wave * 16 + (lane >> 5) * 8;
  const float* vsrc = vb + (size_t)2 * p * 2048 + chbase;     // + kt*64*2048 per tile
  // K staging: wave stages keys [wave*16, +16); 8 fp32 ch per lane, rows coalesced
  int krow = wave * 16 + (lane >> 3);
  int kch  = (lane & 7) * 8;
  const float* ksrc = kb + (size_t)krow * 2048 + kch;         // + kt*64*2048 per tile
  int kdofs = krow * 72 + kch;
  int vdofs_base = 2 * p;

  // prologue: stage K(0), V(0) into buf 0
  {
    f32x4 ka0 = *(const f32x4*)ksrc;
    f32x4 ka1 = *(const f32x4*)(ksrc + 4);
    f32x4 kb0 = *(const f32x4*)(ksrc + (size_t)8 * 2048);
    f32x4 kb1 = *(const f32x4*)(ksrc + (size_t)8 * 2048 + 4);
    *(u16x8*)(&Kt[0][kdofs]) = cvt8(ka0, ka1);
    *(u16x8*)(&Kt[0][kdofs + 8 * 72]) = cvt8(kb0, kb1);
    f32x4 v0a = *(const f32x4*)vsrc;
    f32x4 v0b = *(const f32x4*)(vsrc + 4);
    f32x4 v1a = *(const f32x4*)(vsrc + 2048);
    f32x4 v1b = *(const f32x4*)(vsrc + 2048 + 4);
#pragma unroll
    for (int c = 0; c < 4; ++c) {
      u32 pk = (u32)f2b(v0a[c]) | ((u32)f2b(v1a[c]) << 16);
      *(u32*)(&Vt[0][(chbase + c) * 72 + vdofs_base]) = pk;
      u32 pk2 = (u32)f2b(v0b[c]) | ((u32)f2b(v1b[c]) << 16);
      *(u32*)(&Vt[0][(chbase + 4 + c) * 72 + vdofs_base]) = pk2;
    }
  }
  __syncthreads();

  f32x4 oacc[2][4] = {};
  float l_i[2][4] = {};

  for (int kt = 0; kt < 32; ++kt) {
    int cur = kt & 1;
    // QK: kf shared by both q-frags
    f32x4 sacc[2][4] = {};
    const u16* ktc = Kt[cur];
#pragma unroll
    for (int nt = 0; nt < 4; ++nt) {
      const u16* kr = ktc + (nt * 16 + l15) * 72 + quad * 8;
      bf16x8 kfa = *(const bf16x8*)kr;
      bf16x8 kfb = *(const bf16x8*)(kr + 32);
      sacc[0][nt] = __builtin_amdgcn_mfma_f32_16x16x32_bf16(qf[0][0], kfa, sacc[0][nt], 0, 0, 0);
      sacc[0][nt] = __builtin_amdgcn_mfma_f32_16x16x32_bf16(qf[0][1], kfb, sacc[0][nt], 0, 0, 0);
      sacc[1][nt] = __builtin_amdgcn_mfma_f32_16x16x32_bf16(qf[1][0], kfa, sacc[1][nt], 0, 0, 0);
      sacc[1][nt] = __builtin_amdgcn_mfma_f32_16x16x32_bf16(qf[1][1], kfb, sacc[1][nt], 0, 0, 0);
    }
    // prefetch K(kt+1), V(kt+1) fp32 into registers (consumed at end of iter)
    f32x4 ka0, ka1, kb0, kb1, v0a, v0b, v1a, v1b;
    if (kt < 31) {
      const float* ks2 = ksrc + (size_t)(kt + 1) * 64 * 2048;
      ka0 = *(const f32x4*)ks2;
      ka1 = *(const f32x4*)(ks2 + 4);
      kb0 = *(const f32x4*)(ks2 + (size_t)8 * 2048);
      kb1 = *(const f32x4*)(ks2 + (size_t)8 * 2048 + 4);
      const float* vs2 = vsrc + (size_t)(kt + 1) * 64 * 2048;
      v0a = *(const f32x4*)vs2;
      v0b = *(const f32x4*)(vs2 + 4);
      v1a = *(const f32x4*)(vs2 + 2048);
      v1b = *(const f32x4*)(vs2 + 2048 + 4);
    }
    // p = 2^s; P write; per-lane l partial
#pragma unroll
    for (int f = 0; f < 2; ++f) {
#pragma unroll
      for (int r = 0; r < 4; ++r) {
        float p0 = __builtin_amdgcn_exp2f(sacc[f][0][r]);
        float p1 = __builtin_amdgcn_exp2f(sacc[f][1][r]);
        float p2 = __builtin_amdgcn_exp2f(sacc[f][2][r]);
        float p3 = __builtin_amdgcn_exp2f(sacc[f][3][r]);
        l_i[f][r] += (p0 + p1) + (p2 + p3);
        u16* prow = Pw + (f * 16 + quad * 4 + r) * 72 + l15;
        prow[0]  = f2b(p0);
        prow[16] = f2b(p1);
        prow[32] = f2b(p2);
        prow[48] = f2b(p3);
      }
    }
    // PV: vf shared by both frags
    bf16x8 pf[2][2];
#pragma unroll
    for (int f = 0; f < 2; ++f) {
      pf[f][0] = *(const bf16x8*)(Pw + (f * 16 + l15) * 72 + quad * 8);
      pf[f][1] = *(const bf16x8*)(Pw + (f * 16 + l15) * 72 + 32 + quad * 8);
    }
    const u16* vt = Vt[cur];
#pragma unroll
    for (int nt = 0; nt < 4; ++nt) {
      const u16* vr = vt + (nt * 16 + l15) * 72 + quad * 8;
      bf16x8 vf0 = *(const bf16x8*)vr;
      bf16x8 vf1 = *(const bf16x8*)(vr + 32);
      oacc[0][nt] = __builtin_amdgcn_mfma_f32_16x16x32_bf16(pf[0][0], vf0, oacc[0][nt], 0, 0, 0);
      oacc[0][nt] = __builtin_amdgcn_mfma_f32_16x16x32_bf16(pf[0][1], vf1, oacc[0][nt], 0, 0, 0);
      oacc[1][nt] = __builtin_amdgcn_mfma_f32_16x16x32_bf16(pf[1][0], vf0, oacc[1][nt], 0, 0, 0);
      oacc[1][nt] = __builtin_amdgcn_mfma_f32_16x16x32_bf16(pf[1][1], vf1, oacc[1][nt], 0, 0, 0);
    }
    // stage next tile (cvt fp32->bf16 in-register) into other buffer
    if (kt < 31) {
      u16* kd = Kt[cur ^ 1];
      *(u16x8*)(&kd[kdofs]) = cvt8(ka0, ka1);
      *(u16x8*)(&kd[kdofs + 8 * 72]) = cvt8(kb0, kb1);
      u16* vd = Vt[cur ^ 1];
#pragma unroll
      for (int c = 0; c < 4; ++c) {
        u32 pk = (u32)f2b(v0a[c]) | ((u32)f2b(v1a[c]) << 16);
        *(u32*)(&vd[(chbase + c) * 72 + vdofs_base]) = pk;
        u32 pk2 = (u32)f2b(v0b[c]) | ((u32)f2b(v1b[c]) << 16);
        *(u32*)(&vd[(chbase + 4 + c) * 72 + vdofs_base]) = pk2;
      }
    }
    __syncthreads();
  }
  // reduce l across the 16 lanes of each quad-row group
#pragma unroll
  for (int f = 0; f < 2; ++f)
#pragma unroll
    for (int r = 0; r < 4; ++r) {
      float l = l_i[f][r];
      l += __shfl_xor(l, 1);
      l += __shfl_xor(l, 2);
      l += __shfl_xor(l, 4);
      l += __shfl_xor(l, 8);
      l_i[f][r] = l;
    }
  // vsig inline (hbuf: c = h[ch], f = h[1024+ch])
  float vsg[4];
#pragma unroll
  for (int nt = 0; nt < 4; ++nt) {
    int ch = h * 64 + nt * 16 + l15;
    vsg[nt] = sigm(hbuf[1024 + ch]) * tanhf(hbuf[ch]);
  }
  // epilogue: /l, *vsig, write (s,b,H) fp32
#pragma unroll
  for (int f = 0; f < 2; ++f)
#pragma unroll
    for (int r = 0; r < 4; ++r) {
      int sq = q0 + f * 64 + wave * 16 + quad * 4 + r;
      float inv = 1.0f / l_i[f][r];
      float* orow = out + ((size_t)sq * 2 + b) * 1024 + h * 64;
#pragma unroll
      for (int nt = 0; nt < 4; ++nt)
        orow[nt * 16 + l15] = oacc[f][nt][r] * inv * vsg[nt];
    }
}

extern "C" void kernel_launch(void* const* d_in, const int* in_sizes, int n_in,
                              void* d_out, int out_size, void* d_ws, size_t ws_size,
                              hipStream_t stream) {
  (void)in_sizes; (void)n_in; (void)out_size; (void)ws_size;
  const float* query = (const float*)d_in[0];
  const float* key   = (const float*)d_in[1];
  const float* value = (const float*)d_in[2];
  const float* qs    = (const float*)d_in[3];
  const float* ksp   = (const float*)d_in[4];
  const float* vs    = (const float*)d_in[5];
  const float* vq_w  = (const float*)d_in[6];
  const float* vq_b  = (const float*)d_in[7];
  const float* ql_w  = (const float*)d_in[8];
  const float* ql_b  = (const float*)d_in[9];
  const float* ln_g  = (const float*)d_in[10];
  const float* ln_b  = (const float*)d_in[11];
  float* out = (float*)d_out;

  float* ws = (float*)d_ws;
  float* h   = ws;                                  // 2048 f32
  u16* qpre  = (u16*)(ws + 4096);                   // 4 x 4096x1024 bf16 (32 MB)
  u16* qbf   = qpre + (size_t)4 * 4096 * 1024;      // query bf16 (16 MB); qatt aliases
  u16* qatt  = qbf;                                 // ln writes after gemm's last read
  u16* wbf   = qbf + (size_t)4096 * 2048;           // ql_w bf16 (4 MB)

  hipLaunchKernelGGL(k_cvt2, dim3(10240), dim3(256), 0, stream,
                     (const float4*)query, (u16x4*)qbf,
                     (const float4*)ql_w,  (u16x4*)wbf);
  hipLaunchKernelGGL(k_h,    dim3(512),  dim3(256), 0, stream, vs, vq_w, vq_b, h);
  hipLaunchKernelGGL(k_gemm, dim3(1024), dim3(256), 0, stream, qbf, wbf, qpre);
  hipLaunchKernelGGL(k_ln,   dim3(4096), dim3(256), 0, stream, qpre,
                     ql_b, ln_g, ln_b, qs, ksp, qatt);
  hipLaunchKernelGGL(k_attn, dim3(512),  dim3(256), 0, stream, qatt, key, value, h, out);
}